// Round 1
// baseline (1277.215 us; speedup 1.0000x reference)
//
#include <hip/hip_runtime.h>
#include <cstddef>
#include <cstdint>

#define NNODES    50000
#define DPAPER    256
#define DAUTHOR   128
#define PDIM      128
#define KDIM      16
#define NEDGE     800000
#define NEG_SLOPE 0.01f

// ---------------- workspace layout (float offsets) ----------------
// Combined matrices: C_u = Ws[:, :128] @ Wp_src  (K x D_src)
//                    C_v = Ws[:, 128:] @ Wp_dst  (K x D_dst)
// bias[k] = bs[k] + Ws[:, :128] @ bp_src + Ws[:, 128:] @ bp_dst
// Node score tables: Su[n][k] = x_src[n] . C_u[k],  Sv[n][k] = x_dst[n] . C_v[k]
enum : int {
  OFF_CWU = 0,                    // writes: author-side C  [16][128]
  OFF_CWV = OFF_CWU + 16 * 128,   // writes: paper-side  C  [16][256]
  OFF_CCU = OFF_CWV + 16 * 256,   // cites:  src-paper   C  [16][256]
  OFF_CCV = OFF_CCU + 16 * 256,   // cites:  dst-paper   C  [16][256]
  OFF_BW  = OFF_CCV + 16 * 256,   // writes bias [16]
  OFF_BC  = OFF_BW + 16,          // cites  bias [16]
  OFF_SUW = OFF_BC + 16,          // Su_writes  [50000][16]
  OFF_SVW = OFF_SUW + NNODES * 16,
  OFF_SUC = OFF_SVW + NNODES * 16,
  OFF_SVC = OFF_SUC + NNODES * 16,
};

// ---------------- kernel 1: fold Ws @ Wp into combined matrices ----------------
__global__ void combine_kernel(const float* __restrict__ Wp_paper,   // [128][256]
                               const float* __restrict__ bp_paper,   // [128]
                               const float* __restrict__ Wp_author,  // [128][128]
                               const float* __restrict__ bp_author,  // [128]
                               const float* __restrict__ Ws_w,       // [16][256]
                               const float* __restrict__ bs_w,       // [16]
                               const float* __restrict__ Ws_c,       // [16][256]
                               const float* __restrict__ bs_c,       // [16]
                               float* __restrict__ ws) {
  int idx = blockIdx.x * blockDim.x + threadIdx.x;
  if (idx < 2048) {                       // Cw_u[k][d], d < 128
    int k = idx >> 7, d = idx & 127;
    float s = 0.f;
    for (int p = 0; p < 128; ++p) s += Ws_w[k * 256 + p] * Wp_author[p * 128 + d];
    ws[OFF_CWU + idx] = s;
  } else if (idx < 6144) {                // Cw_v[k][d], d < 256
    int t = idx - 2048; int k = t >> 8, d = t & 255;
    float s = 0.f;
    for (int p = 0; p < 128; ++p) s += Ws_w[k * 256 + 128 + p] * Wp_paper[p * 256 + d];
    ws[OFF_CWV + t] = s;
  } else if (idx < 10240) {               // Cc_u[k][d], d < 256
    int t = idx - 6144; int k = t >> 8, d = t & 255;
    float s = 0.f;
    for (int p = 0; p < 128; ++p) s += Ws_c[k * 256 + p] * Wp_paper[p * 256 + d];
    ws[OFF_CCU + t] = s;
  } else if (idx < 14336) {               // Cc_v[k][d], d < 256
    int t = idx - 10240; int k = t >> 8, d = t & 255;
    float s = 0.f;
    for (int p = 0; p < 128; ++p) s += Ws_c[k * 256 + 128 + p] * Wp_paper[p * 256 + d];
    ws[OFF_CCV + t] = s;
  } else if (idx < 14336 + 32) {          // folded biases
    int t = idx - 14336;
    int k = t & 15;
    if (t < 16) {
      float s = bs_w[k];
      for (int p = 0; p < 128; ++p)
        s += Ws_w[k * 256 + p] * bp_author[p] + Ws_w[k * 256 + 128 + p] * bp_paper[p];
      ws[OFF_BW + k] = s;
    } else {
      float s = bs_c[k];
      for (int p = 0; p < 128; ++p)
        s += Ws_c[k * 256 + p] * bp_paper[p] + Ws_c[k * 256 + 128 + p] * bp_paper[p];
      ws[OFF_BC + k] = s;
    }
  }
}

// ---------------- kernel 2a: author node scores (Su_writes) ----------------
// Su_w[n][k] = x_author[n] . Cw_u[k]  (D=128)
__global__ __launch_bounds__(64) void author_scores(const float* __restrict__ x,
                                                    const float* __restrict__ ws,
                                                    float* __restrict__ out) {
  int n = blockIdx.x * blockDim.x + threadIdx.x;
  if (n >= NNODES) return;
  const float* __restrict__ C = ws + OFF_CWU;  // [16][128], wave-uniform reads -> s_load
  const float4* __restrict__ xr = (const float4*)(x + (size_t)n * 128);
  float acc[16];
#pragma unroll
  for (int k = 0; k < 16; ++k) acc[k] = 0.f;
#pragma unroll 4
  for (int j = 0; j < 32; ++j) {
    float4 xv = xr[j];
#pragma unroll
    for (int k = 0; k < 16; ++k) {
      const float* c = C + k * 128 + 4 * j;
      acc[k] += xv.x * c[0] + xv.y * c[1] + xv.z * c[2] + xv.w * c[3];
    }
  }
  float4* o = (float4*)(out + (size_t)n * 16);
#pragma unroll
  for (int q = 0; q < 4; ++q)
    o[q] = make_float4(acc[4 * q], acc[4 * q + 1], acc[4 * q + 2], acc[4 * q + 3]);
}

// ---------------- kernel 2b: paper node scores (Sv_writes, Su_cites, Sv_cites) ----------------
__global__ __launch_bounds__(64) void paper_scores(const float* __restrict__ x,
                                                   const float* __restrict__ ws,
                                                   float* __restrict__ svw,
                                                   float* __restrict__ suc,
                                                   float* __restrict__ svc) {
  int n = blockIdx.x * blockDim.x + threadIdx.x;
  if (n >= NNODES) return;
  const float* __restrict__ C0 = ws + OFF_CWV;  // [16][256]
  const float* __restrict__ C1 = ws + OFF_CCU;
  const float* __restrict__ C2 = ws + OFF_CCV;
  const float4* __restrict__ xr = (const float4*)(x + (size_t)n * 256);
  float a0[16], a1[16], a2[16];
#pragma unroll
  for (int k = 0; k < 16; ++k) { a0[k] = 0.f; a1[k] = 0.f; a2[k] = 0.f; }
#pragma unroll 2
  for (int j = 0; j < 64; ++j) {
    float4 xv = xr[j];
#pragma unroll
    for (int k = 0; k < 16; ++k) {
      const float* c0 = C0 + k * 256 + 4 * j;
      a0[k] += xv.x * c0[0] + xv.y * c0[1] + xv.z * c0[2] + xv.w * c0[3];
      const float* c1 = C1 + k * 256 + 4 * j;
      a1[k] += xv.x * c1[0] + xv.y * c1[1] + xv.z * c1[2] + xv.w * c1[3];
      const float* c2 = C2 + k * 256 + 4 * j;
      a2[k] += xv.x * c2[0] + xv.y * c2[1] + xv.z * c2[2] + xv.w * c2[3];
    }
  }
  float4* o0 = (float4*)(svw + (size_t)n * 16);
  float4* o1 = (float4*)(suc + (size_t)n * 16);
  float4* o2 = (float4*)(svc + (size_t)n * 16);
#pragma unroll
  for (int q = 0; q < 4; ++q) {
    o0[q] = make_float4(a0[4 * q], a0[4 * q + 1], a0[4 * q + 2], a0[4 * q + 3]);
    o1[q] = make_float4(a1[4 * q], a1[4 * q + 1], a1[4 * q + 2], a1[4 * q + 3]);
    o2[q] = make_float4(a2[4 * q], a2[4 * q + 1], a2[4 * q + 2], a2[4 * q + 3]);
  }
}

// ---------------- kernel 3: per-edge softmax + b @ A ----------------
// One thread per edge. logits = Su[src] + Sv[dst] + bias; b = softmax(lrelu(logits));
// out[e] = b @ A. A reads are wave-uniform -> scalar loads; b stays in VGPRs.
__global__ __launch_bounds__(256) void edge_kernel(const int* __restrict__ ei,     // [2][E]
                                                   const float* __restrict__ Su,   // [N][16]
                                                   const float* __restrict__ Sv,   // [N][16]
                                                   const float* __restrict__ bias, // [16]
                                                   const float* __restrict__ A,    // [16][128]
                                                   float* __restrict__ out) {      // [E][128]
  int e = blockIdx.x * blockDim.x + threadIdx.x;
  if (e >= NEDGE) return;
  int src = ei[e];
  int dst = ei[NEDGE + e];
  const float4* __restrict__ su4 = (const float4*)(Su + (size_t)src * 16);
  const float4* __restrict__ sv4 = (const float4*)(Sv + (size_t)dst * 16);
  float lo[16];
#pragma unroll
  for (int q = 0; q < 4; ++q) {
    float4 a = su4[q];
    float4 b = sv4[q];
    lo[4 * q + 0] = a.x + b.x + bias[4 * q + 0];
    lo[4 * q + 1] = a.y + b.y + bias[4 * q + 1];
    lo[4 * q + 2] = a.z + b.z + bias[4 * q + 2];
    lo[4 * q + 3] = a.w + b.w + bias[4 * q + 3];
  }
  // leaky_relu(x) = max(x, slope*x) for 0 < slope < 1
  float m = -1e30f;
#pragma unroll
  for (int k = 0; k < 16; ++k) {
    lo[k] = fmaxf(lo[k], NEG_SLOPE * lo[k]);
    m = fmaxf(m, lo[k]);
  }
  float s = 0.f;
#pragma unroll
  for (int k = 0; k < 16; ++k) {
    lo[k] = __expf(lo[k] - m);
    s += lo[k];
  }
  float inv = 1.0f / s;
#pragma unroll
  for (int k = 0; k < 16; ++k) lo[k] *= inv;

  const float4* __restrict__ A4 = (const float4*)A;  // [16][32] float4, uniform index
  float4* __restrict__ o4 = (float4*)(out + (size_t)e * 128);
#pragma unroll 4
  for (int j = 0; j < 32; ++j) {
    float4 acc = make_float4(0.f, 0.f, 0.f, 0.f);
#pragma unroll
    for (int k = 0; k < 16; ++k) {
      float4 a = A4[k * 32 + j];
      acc.x += lo[k] * a.x;
      acc.y += lo[k] * a.y;
      acc.z += lo[k] * a.z;
      acc.w += lo[k] * a.w;
    }
    o4[j] = acc;
  }
}

extern "C" void kernel_launch(void* const* d_in, const int* in_sizes, int n_in,
                              void* d_out, int out_size, void* d_ws, size_t ws_size,
                              hipStream_t stream) {
  const float* x_paper   = (const float*)d_in[0];   // [50000][256]
  const float* x_author  = (const float*)d_in[1];   // [50000][128]
  const float* Wp_paper  = (const float*)d_in[2];   // [128][256]
  const float* bp_paper  = (const float*)d_in[3];   // [128]
  const float* Wp_author = (const float*)d_in[4];   // [128][128]
  const float* bp_author = (const float*)d_in[5];   // [128]
  const float* Ws_w      = (const float*)d_in[6];   // [16][256]
  const float* bs_w      = (const float*)d_in[7];   // [16]
  const float* A_w       = (const float*)d_in[8];   // [16][128]
  const float* Ws_c      = (const float*)d_in[9];   // [16][256]
  const float* bs_c      = (const float*)d_in[10];  // [16]
  const float* A_c       = (const float*)d_in[11];  // [16][128]
  const int*   ei_w      = (const int*)d_in[12];    // [2][800000]
  const int*   ei_c      = (const int*)d_in[13];    // [2][800000]

  float* ws  = (float*)d_ws;
  float* out = (float*)d_out;  // p_writes [800000][128] then p_cites [800000][128]

  // 1) fold projection + scorer weights: ~14K dots of length 128
  combine_kernel<<<(14336 + 32 + 255) / 256, 256, 0, stream>>>(
      Wp_paper, bp_paper, Wp_author, bp_author, Ws_w, bs_w, Ws_c, bs_c, ws);

  // 2) per-node score tables [50000][16]
  author_scores<<<(NNODES + 63) / 64, 64, 0, stream>>>(x_author, ws, ws + OFF_SUW);
  paper_scores<<<(NNODES + 63) / 64, 64, 0, stream>>>(x_paper, ws, ws + OFF_SVW,
                                                      ws + OFF_SUC, ws + OFF_SVC);

  // 3) per-edge softmax + b @ A  (E = 800000 = 3125 * 256, exact)
  edge_kernel<<<(NEDGE + 255) / 256, 256, 0, stream>>>(
      ei_w, ws + OFF_SUW, ws + OFF_SVW, ws + OFF_BW, A_w, out);
  edge_kernel<<<(NEDGE + 255) / 256, 256, 0, stream>>>(
      ei_c, ws + OFF_SUC, ws + OFF_SVC, ws + OFF_BC, A_c, out + (size_t)NEDGE * 128);
}